// Round 5
// baseline (2117.256 us; speedup 1.0000x reference)
//
#include <hip/hip_runtime.h>
#include <math.h>

#define DIM 4096
#define RDIM 16
#define RIDGE 1e-5f
#define NCHUNK 16   // buildA m-chunks (256 rows each)
#define NPK 136     // packed upper-tri size
#define NSL 128     // tpart slices (= grid.y of it_c)
#define SROWS 32    // rows per it_c block
#define NSLA 256    // spart slices (= grid.y of it_a)
#define SROWSA 16   // rows per it_a block

__device__ __forceinline__ int pidx(int r, int s) { return r * (31 - r) / 2 + s; } // r<=s

__device__ __forceinline__ float alpha_of(float cl) {
    return cl * (1.f - erff(sqrtf(cl))) +
           0.5f * (erff(cl * 0.70710678118f) -
                   0.79788456080f * cl * expf(-0.5f * cl * cl));
}

// ---------------- transpose X -> Xt (Xt lives in d_out until final GEMM) ----
__global__ void __launch_bounds__(256) k_transpose(const float* __restrict__ X,
                                                   float* __restrict__ Xt) {
    __shared__ float tile[64][65];
    int bx = blockIdx.x, by = blockIdx.y;
    int lx = threadIdx.x & 63;
    int ly = threadIdx.x >> 6;
#pragma unroll
    for (int i = 0; i < 16; ++i) {
        int r = ly + i * 4;
        tile[r][lx] = X[(size_t)(by * 64 + r) * DIM + bx * 64 + lx];
    }
    __syncthreads();
#pragma unroll
    for (int i = 0; i < 16; ++i) {
        int r = ly + i * 4;
        Xt[(size_t)(bx * 64 + r) * DIM + by * 64 + lx] = tile[lx][r];
    }
}

// ---------------- observed-count per column (setup only, atomics OK) -------
__global__ void __launch_bounds__(256) k_count(const float* __restrict__ Xp,
                                               float* __restrict__ cnt) {
    int c = blockIdx.x * 256 + threadIdx.x;
    int m0 = blockIdx.y * 256;
    float acc = 0.f;
    for (int m = 0; m < 256; ++m) {
        float x = Xp[(size_t)(m0 + m) * DIM + c];
        acc += (x != 0.f) ? 1.f : 0.f;
    }
    atomicAdd(&cnt[c], acc);
}

// ---------------- init copies ----------------------------------------------
__global__ void k_init_uc(const float* __restrict__ U, float* __restrict__ Uc) {
    int i = blockIdx.x * 256 + threadIdx.x;
    ((float4*)Uc)[i] = ((const float4*)U)[i];
}
__global__ void k_init_vt(const float* __restrict__ V, float* __restrict__ Vtb) {
    int n = blockIdx.x * 256 + threadIdx.x;
#pragma unroll
    for (int r = 0; r < RDIM; ++r) Vtb[(size_t)n * RDIM + r] = V[(size_t)r * DIM + n];
}

// ---------------- A partials, 8 cols/thread, packed stores -----------------
// block 256: g = tid&15 (8-col group), j = tid>>4 (A row). grid (32, NCHUNK).
__global__ void __launch_bounds__(256) k_buildA(const float* __restrict__ Xp,
                                                const float* __restrict__ D,
                                                float* __restrict__ Apart) {
    __shared__ float ds[128 * RDIM];
    const int g = threadIdx.x & 15;
    const int j = threadIdx.x >> 4;
    const int cbase = blockIdx.x * 128 + g * 8;
    const int m0 = blockIdx.y * 256;

    float a[8][16];
#pragma unroll
    for (int i = 0; i < 8; ++i)
#pragma unroll
        for (int s = 0; s < 16; ++s) a[i][s] = 0.f;

    for (int sub = 0; sub < 2; ++sub) {
        const float* Dsub = D + (size_t)(m0 + sub * 128) * RDIM;
        ((float4*)ds)[threadIdx.x]       = ((const float4*)Dsub)[threadIdx.x];
        ((float4*)ds)[256 + threadIdx.x] = ((const float4*)Dsub)[256 + threadIdx.x];
        __syncthreads();

        for (int m = 0; m < 128; ++m) {
            const float* xrow = Xp + (size_t)(m0 + sub * 128 + m) * DIM + cbase;
            float4 xa = *(const float4*)xrow;
            float4 xb = *(const float4*)(xrow + 4);
            float u[16];
#pragma unroll
            for (int q = 0; q < 4; ++q) {
                float4 u4 = ((const float4*)(ds + m * RDIM))[q];
                u[q * 4 + 0] = u4.x; u[q * 4 + 1] = u4.y;
                u[q * 4 + 2] = u4.z; u[q * 4 + 3] = u4.w;
            }
            float uj = ds[m * RDIM + j];
            float p[8];
            p[0] = (xa.x != 0.f) ? uj : 0.f;
            p[1] = (xa.y != 0.f) ? uj : 0.f;
            p[2] = (xa.z != 0.f) ? uj : 0.f;
            p[3] = (xa.w != 0.f) ? uj : 0.f;
            p[4] = (xb.x != 0.f) ? uj : 0.f;
            p[5] = (xb.y != 0.f) ? uj : 0.f;
            p[6] = (xb.z != 0.f) ? uj : 0.f;
            p[7] = (xb.w != 0.f) ? uj : 0.f;
#pragma unroll
            for (int s = 0; s < 16; ++s) {
#pragma unroll
                for (int i = 0; i < 8; ++i) a[i][s] += p[i] * u[s];
            }
        }
        __syncthreads();
    }
#pragma unroll
    for (int i = 0; i < 8; ++i) {
        size_t base = ((size_t)blockIdx.y * DIM + (cbase + i)) * NPK + (size_t)j * (31 - j) / 2;
#pragma unroll
        for (int s = 0; s < 16; ++s)
            if (s >= j) Apart[base + s] = a[i][s];
    }
}

// ---------------- coalesced chunk reduction: Ared = sum_ch Apart -----------
// grid 544 blocks * 256 thr * float4 == DIM*NPK floats exactly.
__global__ void __launch_bounds__(256) k_reduceA(const float* __restrict__ Apart,
                                                 float* __restrict__ Ared) {
    int idx = blockIdx.x * 256 + threadIdx.x;
    float4 acc = make_float4(0.f, 0.f, 0.f, 0.f);
#pragma unroll
    for (int ch = 0; ch < NCHUNK; ++ch) {
        float4 v = ((const float4*)(Apart + (size_t)ch * DIM * NPK))[idx];
        acc.x += v.x; acc.y += v.y; acc.z += v.z; acc.w += v.w;
    }
    ((float4*)Ared)[idx] = acc;
}

// ------- invert 16x16 SPD from packed Ared ---------------------------------
// block 128 thr (8 matrices), grid 512.
__global__ void __launch_bounds__(128) k_invert(const float* __restrict__ Ared,
                                                float* __restrict__ Ainv) {
    int gt = blockIdx.x * 128 + threadIdx.x;
    int c = gt >> 4;
    int j = gt & 15;

    float a[16], b[16];
#pragma unroll
    for (int s = 0; s < 16; ++s) {
        int r0 = j < s ? j : s;
        int s0 = j < s ? s : j;
        a[s] = Ared[(size_t)c * NPK + pidx(r0, s0)];
        b[s] = 0.f;
    }
    a[j] += RIDGE;
    b[j] = 1.f;

#pragma unroll
    for (int k = 0; k < RDIM; ++k) {
        float pivA[16], pivB[16];
#pragma unroll
        for (int s = 0; s < 16; ++s) {
            pivA[s] = __shfl(a[s], k, 16);
            pivB[s] = __shfl(b[s], k, 16);
        }
        float pinv = 1.f / pivA[k];
        float f = a[k];
        if (j == k) {
#pragma unroll
            for (int s = 0; s < 16; ++s) { a[s] = pivA[s] * pinv; b[s] = pivB[s] * pinv; }
        } else {
#pragma unroll
            for (int s = 0; s < 16; ++s) {
                a[s] -= f * pinv * pivA[s];
                b[s] -= f * pinv * pivB[s];
            }
        }
    }
#pragma unroll
    for (int s = 0; s < 16; ++s) Ainv[(size_t)c * 256 + j * 16 + s] = b[s];
}

// ---------------- sigma: sum NSLA spart slices once per column -------------
// grid 64 blocks, block 256: thread = (column within 64, slice-quarter).
__global__ void __launch_bounds__(256) k_sig(const float* __restrict__ spart,
                                             const float* __restrict__ cnt,
                                             const float* __restrict__ cvec,
                                             const float* __restrict__ lvec,
                                             int layer, float* __restrict__ sig) {
    __shared__ float red[256];
    int c = blockIdx.x * 64 + (threadIdx.x & 63);
    int part = threadIdx.x >> 6;  // 0..3
    float s = 0.f;
    for (int sl = part * 64; sl < part * 64 + 64; ++sl)
        s += spart[(size_t)sl * DIM + c];
    red[threadIdx.x] = s;
    __syncthreads();
    if (part == 0) {
        s = red[threadIdx.x] + red[threadIdx.x + 64] +
            red[threadIdx.x + 128] + red[threadIdx.x + 192];
        float cl = cvec[layer], ll = lvec[layer];
        float al = alpha_of(cl);
        sig[c] = ll * sqrtf(s) * rsqrtf(2.f * cnt[c] * al);
    }
}

// ---------------- pass 1: psi^2 slice partials, 8 cols/thread --------------
// grid (2, NSLA), block 256.
__global__ void __launch_bounds__(256) k_it_a(const float* __restrict__ Xp,
                                              const float* __restrict__ D,
                                              const float* __restrict__ B,
                                              const float* __restrict__ sig,
                                              const float* __restrict__ sigma,
                                              const float* __restrict__ cvec,
                                              int layer, int use_s0,
                                              float* __restrict__ spart_out) {
    __shared__ float ds[SROWSA * RDIM];  // 1 KB
    const int c = blockIdx.x * 2048 + threadIdx.x * 8;
    const int m0 = blockIdx.y * SROWSA;
    if (threadIdx.x < SROWSA * RDIM / 4)
        ((float4*)ds)[threadIdx.x] = ((const float4*)(D + (size_t)m0 * RDIM))[threadIdx.x];

    float cl = cvec[layer];
    float invsg[8];
    if (use_s0) {
        float is0 = 1.f / sigma[0];
#pragma unroll
        for (int i = 0; i < 8; ++i) invsg[i] = is0;
    } else {
#pragma unroll
        for (int i = 0; i < 8; ++i) invsg[i] = 1.f / sig[c + i];
    }
    float beta[8][16];
#pragma unroll
    for (int i = 0; i < 8; ++i)
#pragma unroll
        for (int q = 0; q < 4; ++q) {
            float4 t4 = ((const float4*)(B + (size_t)(c + i) * RDIM))[q];
            beta[i][q * 4 + 0] = t4.x; beta[i][q * 4 + 1] = t4.y;
            beta[i][q * 4 + 2] = t4.z; beta[i][q * 4 + 3] = t4.w;
        }
    __syncthreads();

    float acc[8];
#pragma unroll
    for (int i = 0; i < 8; ++i) acc[i] = 0.f;

    for (int m = 0; m < SROWSA; ++m) {
        float u[16];
#pragma unroll
        for (int q = 0; q < 4; ++q) {
            float4 u4 = ((const float4*)(ds + m * RDIM))[q];
            u[q * 4 + 0] = u4.x; u[q * 4 + 1] = u4.y;
            u[q * 4 + 2] = u4.z; u[q * 4 + 3] = u4.w;
        }
        const float* xrow = Xp + (size_t)(m0 + m) * DIM + c;
        float4 xa = *(const float4*)xrow;
        float4 xb = *(const float4*)(xrow + 4);
        float xv[8] = {xa.x, xa.y, xa.z, xa.w, xb.x, xb.y, xb.z, xb.w};
#pragma unroll
        for (int i = 0; i < 8; ++i) {
            float dot = 0.f;
#pragma unroll
            for (int s = 0; s < 16; ++s) dot += u[s] * beta[i][s];
            float res = (xv[i] != 0.f) ? (xv[i] - dot) : 0.f;
            float psi = fminf(fmaxf(res * invsg[i], -cl), cl);
            acc[i] += psi * psi;
        }
    }
    float* outp = spart_out + (size_t)blockIdx.y * DIM + c;
    *(float4*)outp       = make_float4(acc[0], acc[1], acc[2], acc[3]);
    *(float4*)(outp + 4) = make_float4(acc[4], acc[5], acc[6], acc[7]);
}

// ---------------- pass 2: t slice partials, 4 cols/thread ------------------
// grid (4, NSL), block 256.
__global__ void __launch_bounds__(256) k_it_c(const float* __restrict__ Xp,
                                              const float* __restrict__ D,
                                              const float* __restrict__ B,
                                              const float* __restrict__ sig,
                                              const float* __restrict__ cvec,
                                              int layer,
                                              float* __restrict__ tpart) {
    __shared__ float ds[SROWS * RDIM];
    const int c = blockIdx.x * 1024 + threadIdx.x * 4;
    const int m0 = blockIdx.y * SROWS;
    if (threadIdx.x < SROWS * RDIM / 4)
        ((float4*)ds)[threadIdx.x] = ((const float4*)(D + (size_t)m0 * RDIM))[threadIdx.x];

    float cl = cvec[layer];
    float sg[4], invsg[4];
#pragma unroll
    for (int i = 0; i < 4; ++i) {
        sg[i] = sig[c + i];
        invsg[i] = 1.f / sg[i];
    }
    float beta[4][16];
#pragma unroll
    for (int i = 0; i < 4; ++i)
#pragma unroll
        for (int q = 0; q < 4; ++q) {
            float4 t4 = ((const float4*)(B + (size_t)(c + i) * RDIM))[q];
            beta[i][q * 4 + 0] = t4.x; beta[i][q * 4 + 1] = t4.y;
            beta[i][q * 4 + 2] = t4.z; beta[i][q * 4 + 3] = t4.w;
        }
    __syncthreads();

    float tac[4][16];
#pragma unroll
    for (int i = 0; i < 4; ++i)
#pragma unroll
        for (int s = 0; s < 16; ++s) tac[i][s] = 0.f;

#pragma unroll 2
    for (int m = 0; m < SROWS; ++m) {
        float u[16];
#pragma unroll
        for (int q = 0; q < 4; ++q) {
            float4 u4 = ((const float4*)(ds + m * RDIM))[q];
            u[q * 4 + 0] = u4.x; u[q * 4 + 1] = u4.y;
            u[q * 4 + 2] = u4.z; u[q * 4 + 3] = u4.w;
        }
        float4 x4 = *(const float4*)(Xp + (size_t)(m0 + m) * DIM + c);
        float xv[4] = {x4.x, x4.y, x4.z, x4.w};
#pragma unroll
        for (int i = 0; i < 4; ++i) {
            float dot = 0.f;
#pragma unroll
            for (int s = 0; s < 16; ++s) dot += u[s] * beta[i][s];
            float res = (xv[i] != 0.f) ? (xv[i] - dot) : 0.f;
            float psi2 = fminf(fmaxf(res * invsg[i], -cl), cl);
            float coeff = psi2 * sg[i];
#pragma unroll
            for (int s = 0; s < 16; ++s) tac[i][s] += u[s] * coeff;
        }
    }
    float* tsl = tpart + (size_t)blockIdx.y * DIM * RDIM;
#pragma unroll
    for (int i = 0; i < 4; ++i)
#pragma unroll
        for (int q = 0; q < 4; ++q)
            *(float4*)(tsl + (size_t)(c + i) * RDIM + q * 4) =
                make_float4(tac[i][q * 4 + 0], tac[i][q * 4 + 1],
                            tac[i][q * 4 + 2], tac[i][q * 4 + 3]);
}

// ------- beta update: B += mu * Ainv @ (sum of tpart slices) ---------------
__global__ void __launch_bounds__(256) k_it_d(const float* __restrict__ Ainv,
                                              const float* __restrict__ tpart,
                                              const float* __restrict__ mvec, int layer,
                                              float* __restrict__ B) {
    __shared__ float t_sh[16][16];
    int c0 = blockIdx.x * 16;
    int cl_ = threadIdx.x >> 4;
    int s = threadIdx.x & 15;
    float tv = 0.f;
#pragma unroll 8
    for (int sl = 0; sl < NSL; ++sl)
        tv += tpart[((size_t)sl * DIM + c0 + cl_) * RDIM + s];
    t_sh[cl_][s] = tv;
    __syncthreads();

    int c = c0 + cl_;
    int j = s;
    float ml = mvec[layer];
    float d = 0.f;
#pragma unroll
    for (int q = 0; q < 4; ++q) {
        float4 a4 = *(const float4*)(Ainv + (size_t)c * 256 + j * 16 + q * 4);
        d += a4.x * t_sh[cl_][q * 4 + 0] + a4.y * t_sh[cl_][q * 4 + 1] +
             a4.z * t_sh[cl_][q * 4 + 2] + a4.w * t_sh[cl_][q * 4 + 3];
    }
    B[(size_t)c * RDIM + j] += ml * d;
}

// ---------------- final out = Uc @ Vtb^T -----------------------------------
__global__ void __launch_bounds__(256) k_out(const float* __restrict__ Uc,
                                             const float* __restrict__ Vtb,
                                             float* __restrict__ out) {
    __shared__ float us[64 * RDIM];
    int j = blockIdx.x * 256 + threadIdx.x;
    int i0 = blockIdx.y * 64;
    ((float4*)us)[threadIdx.x] = ((const float4*)(Uc + (size_t)i0 * RDIM))[threadIdx.x];
    float beta[16];
#pragma unroll
    for (int q = 0; q < 4; ++q) {
        float4 t4 = ((const float4*)(Vtb + (size_t)j * RDIM))[q];
        beta[q * 4 + 0] = t4.x; beta[q * 4 + 1] = t4.y;
        beta[q * 4 + 2] = t4.z; beta[q * 4 + 3] = t4.w;
    }
    __syncthreads();
#pragma unroll 4
    for (int r = 0; r < 64; ++r) {
        float dot = 0.f;
#pragma unroll
        for (int q = 0; q < 4; ++q) {
            float4 u4 = ((const float4*)(us + r * RDIM))[q];
            dot += u4.x * beta[q * 4 + 0] + u4.y * beta[q * 4 + 1] +
                   u4.z * beta[q * 4 + 2] + u4.w * beta[q * 4 + 3];
        }
        out[(size_t)(i0 + r) * DIM + j] = dot;
    }
}

extern "C" void kernel_launch(void* const* d_in, const int* in_sizes, int n_in,
                              void* d_out, int out_size, void* d_ws, size_t ws_size,
                              hipStream_t stream) {
    const float* U = (const float*)d_in[0];
    const float* V = (const float*)d_in[1];
    const float* X = (const float*)d_in[2];
    const float* cvec = (const float*)d_in[3];
    const float* lvec = (const float*)d_in[4];
    const float* mvec = (const float*)d_in[5];
    const float* sigma = (const float*)d_in[6];
    float* out = (float*)d_out;

    float* ws = (float*)d_ws;
    // BIG aliased region: Apart (buildA..reduceA) vs tpart+spart (it-phase).
    // Apart = 16*4096*136 = 8,912,896 f; tpart = 128*4096*16 = 8,388,608 f;
    // spart @ tpart+8,388,608 (256*4096 = 1,048,576 f). big = 9,437,184 f.
    float* big    = ws;
    float* Apart  = big;
    float* tpart  = big;
    float* spart  = big + (size_t)NSL * DIM * RDIM;
    float* endbig = big + (size_t)NSL * DIM * RDIM + (size_t)NSLA * DIM;
    float* Ared   = endbig;                       // 4096*136
    float* Ainv   = Ared + (size_t)DIM * NPK;     // 4096*256
    float* sigbuf = Ainv + (size_t)DIM * 256;     // 4096
    float* cntc   = sigbuf + DIM;                 // 4096
    float* cntr   = cntc + DIM;                   // 4096
    float* Uc     = cntr + DIM;                   // 4096*16
    float* Vtb    = Uc + (size_t)DIM * RDIM;      // 4096*16
    float* Xt     = out;  // reuse d_out as transpose scratch until k_out

    // zero only the atomic targets (cntc, cntr — contiguous)
    hipMemsetAsync(cntc, 0, (size_t)2 * DIM * sizeof(float), stream);

    k_transpose<<<dim3(64, 64), 256, 0, stream>>>(X, Xt);
    k_init_uc<<<64, 256, 0, stream>>>(U, Uc);
    k_init_vt<<<16, 256, 0, stream>>>(V, Vtb);
    k_count<<<dim3(16, 16), 256, 0, stream>>>(X, cntc);
    k_count<<<dim3(16, 16), 256, 0, stream>>>(Xt, cntr);

    for (int layer = 0; layer < 3; ++layer) {
        // ---- V step: columns of X, design rows = Uc, beta rows = Vtb ----
        k_buildA<<<dim3(32, NCHUNK), 256, 0, stream>>>(X, Uc, Apart);
        k_reduceA<<<544, 256, 0, stream>>>(Apart, Ared);
        k_invert<<<512, 128, 0, stream>>>(Ared, Ainv);
        k_it_a<<<dim3(2, NSLA), 256, 0, stream>>>(X, Uc, Vtb, sigbuf, sigma, cvec,
                                                  layer, 1, spart);
        k_sig<<<64, 256, 0, stream>>>(spart, cntc, cvec, lvec, layer, sigbuf);
        k_it_c<<<dim3(4, NSL), 256, 0, stream>>>(X, Uc, Vtb, sigbuf, cvec, layer, tpart);
        k_it_d<<<256, 256, 0, stream>>>(Ainv, tpart, mvec, layer, Vtb);
        k_it_a<<<dim3(2, NSLA), 256, 0, stream>>>(X, Uc, Vtb, sigbuf, sigma, cvec,
                                                  layer, 0, spart);
        k_sig<<<64, 256, 0, stream>>>(spart, cntc, cvec, lvec, layer, sigbuf);
        k_it_c<<<dim3(4, NSL), 256, 0, stream>>>(X, Uc, Vtb, sigbuf, cvec, layer, tpart);
        k_it_d<<<256, 256, 0, stream>>>(Ainv, tpart, mvec, layer, Vtb);

        // ---- U step: columns of Xt, design rows = Vtb, beta rows = Uc ----
        k_buildA<<<dim3(32, NCHUNK), 256, 0, stream>>>(Xt, Vtb, Apart);
        k_reduceA<<<544, 256, 0, stream>>>(Apart, Ared);
        k_invert<<<512, 128, 0, stream>>>(Ared, Ainv);
        k_it_a<<<dim3(2, NSLA), 256, 0, stream>>>(Xt, Vtb, Uc, sigbuf, sigma, cvec,
                                                  layer, 1, spart);
        k_sig<<<64, 256, 0, stream>>>(spart, cntr, cvec, lvec, layer, sigbuf);
        k_it_c<<<dim3(4, NSL), 256, 0, stream>>>(Xt, Vtb, Uc, sigbuf, cvec, layer, tpart);
        k_it_d<<<256, 256, 0, stream>>>(Ainv, tpart, mvec, layer, Uc);
        k_it_a<<<dim3(2, NSLA), 256, 0, stream>>>(Xt, Vtb, Uc, sigbuf, sigma, cvec,
                                                  layer, 0, spart);
        k_sig<<<64, 256, 0, stream>>>(spart, cntr, cvec, lvec, layer, sigbuf);
        k_it_c<<<dim3(4, NSL), 256, 0, stream>>>(Xt, Vtb, Uc, sigbuf, cvec, layer, tpart);
        k_it_d<<<256, 256, 0, stream>>>(Ainv, tpart, mvec, layer, Uc);
    }
    k_out<<<dim3(16, 64), 256, 0, stream>>>(Uc, Vtb, out);
}

// Round 6
// 1560.609 us; speedup vs baseline: 1.3567x; 1.3567x over previous
//
#include <hip/hip_runtime.h>
#include <math.h>

#define DIM 4096
#define RDIM 16
#define RIDGE 1e-5f
#define NPKP 144    // padded pair count (9 MFMA tiles of 16)
#define KCH 8       // K-chunks for MFMA buildA
#define NSL 128     // tpart slices (= grid.y of it_c)
#define SROWS 32    // rows per it_c block
#define NSLA 256    // spart slices (= grid.y of it_a)
#define SROWSA 16   // rows per it_a block

typedef __attribute__((ext_vector_type(8))) short bf16x8;
typedef __attribute__((ext_vector_type(4))) float f32x4;

__device__ __forceinline__ int pidx(int r, int s) { return r * (31 - r) / 2 + s; } // r<=s

__device__ __forceinline__ float alpha_of(float cl) {
    return cl * (1.f - erff(sqrtf(cl))) +
           0.5f * (erff(cl * 0.70710678118f) -
                   0.79788456080f * cl * expf(-0.5f * cl * cl));
}

// ---------------- transpose X -> Xt (Xt lives in d_out until final GEMM) ----
__global__ void __launch_bounds__(256) k_transpose(const float* __restrict__ X,
                                                   float* __restrict__ Xt) {
    __shared__ float tile[64][65];
    int bx = blockIdx.x, by = blockIdx.y;
    int lx = threadIdx.x & 63;
    int ly = threadIdx.x >> 6;
#pragma unroll
    for (int i = 0; i < 16; ++i) {
        int r = ly + i * 4;
        tile[r][lx] = X[(size_t)(by * 64 + r) * DIM + bx * 64 + lx];
    }
    __syncthreads();
#pragma unroll
    for (int i = 0; i < 16; ++i) {
        int r = ly + i * 4;
        Xt[(size_t)(bx * 64 + r) * DIM + by * 64 + lx] = tile[lx][r];
    }
}

// ---------------- observed-count per column (setup only, atomics OK) -------
__global__ void __launch_bounds__(256) k_count(const float* __restrict__ Xp,
                                               float* __restrict__ cnt) {
    int c = blockIdx.x * 256 + threadIdx.x;
    int m0 = blockIdx.y * 256;
    float acc = 0.f;
    for (int m = 0; m < 256; ++m) {
        float x = Xp[(size_t)(m0 + m) * DIM + c];
        acc += (x != 0.f) ? 1.f : 0.f;
    }
    atomicAdd(&cnt[c], acc);
}

// ---------------- init copies ----------------------------------------------
__global__ void k_init_uc(const float* __restrict__ U, float* __restrict__ Uc) {
    int i = blockIdx.x * 256 + threadIdx.x;
    ((float4*)Uc)[i] = ((const float4*)U)[i];
}
__global__ void k_init_vt(const float* __restrict__ V, float* __restrict__ Vtb) {
    int n = blockIdx.x * 256 + threadIdx.x;
#pragma unroll
    for (int r = 0; r < RDIM; ++r) Vtb[(size_t)n * RDIM + r] = V[(size_t)r * DIM + n];
}

// ---------------- Pt[rs][m] = bf16(D[m][r] * D[m][s]), pidx order ----------
// grid (16 m-chunks, NPKP), block 256.
__global__ void __launch_bounds__(256) k_prep(const float* __restrict__ D,
                                              unsigned short* __restrict__ Pt) {
    int rs = blockIdx.y;
    int rr = 16, ss = 0;
#pragma unroll
    for (int r = 0; r < 16; ++r) {
        int base = r * (31 - r) / 2;
        if (rs >= base + r && rs <= base + 15) { rr = r; ss = rs - base; }
    }
    int m = blockIdx.x * 256 + threadIdx.x;
    float p = 0.f;
    if (rr < 16) p = D[(size_t)m * RDIM + rr] * D[(size_t)m * RDIM + ss];
    unsigned bits = __float_as_uint(p);
    unsigned short h = (unsigned short)((bits + 0x7FFFu + ((bits >> 16) & 1u)) >> 16);
    Pt[(size_t)rs * DIM + m] = h;
}

// ---------------- MFMA buildA: Apad[kc][c][rs] = P @ W chunks --------------
// XpT row c must be contiguous in the reduction index (Xt for V-step, X for U-step).
// grid (64, KCH), block 256 = 4 waves; wave -> c-tile, blockIdx.y -> k-chunk.
__global__ void __launch_bounds__(256) k_buildA_mfma(const float* __restrict__ XpT,
                                                     const unsigned short* __restrict__ Pt,
                                                     float* __restrict__ Apad) {
    const int wave = threadIdx.x >> 6;
    const int lane = threadIdx.x & 63;
    const int n = lane & 15;
    const int quad = lane >> 4;
    const int ct = blockIdx.x * 4 + wave;   // c-tile 0..255
    const int c = ct * 16 + n;
    const int kbase0 = blockIdx.y * (DIM / KCH);

    f32x4 acc[9];
#pragma unroll
    for (int t = 0; t < 9; ++t) acc[t] = (f32x4){0.f, 0.f, 0.f, 0.f};

    const float* xrow = XpT + (size_t)c * DIM;
#pragma unroll 2
    for (int ks = 0; ks < (DIM / KCH) / 32; ++ks) {
        int kb = kbase0 + ks * 32 + quad * 8;
        float4 xa = *(const float4*)(xrow + kb);
        float4 xb = *(const float4*)(xrow + kb + 4);
        union { bf16x8 v; unsigned u[4]; } bfr;
        bfr.u[0] = (xa.x != 0.f ? 0x3F80u : 0u) | (xa.y != 0.f ? 0x3F800000u : 0u);
        bfr.u[1] = (xa.z != 0.f ? 0x3F80u : 0u) | (xa.w != 0.f ? 0x3F800000u : 0u);
        bfr.u[2] = (xb.x != 0.f ? 0x3F80u : 0u) | (xb.y != 0.f ? 0x3F800000u : 0u);
        bfr.u[3] = (xb.z != 0.f ? 0x3F80u : 0u) | (xb.w != 0.f ? 0x3F800000u : 0u);
#pragma unroll
        for (int t = 0; t < 9; ++t) {
            bf16x8 af = *(const bf16x8*)(Pt + (size_t)(t * 16 + n) * DIM + kb);
            acc[t] = __builtin_amdgcn_mfma_f32_16x16x32_bf16(af, bfr.v, acc[t], 0, 0, 0);
        }
    }
    // C/D layout: col = lane&15 (c), row = quad*4 + reg (rs within tile)
    float* dst0 = Apad + ((size_t)blockIdx.y * DIM + c) * NPKP + quad * 4;
#pragma unroll
    for (int t = 0; t < 9; ++t)
        *(float4*)(dst0 + t * 16) = (float4){acc[t].x, acc[t].y, acc[t].z, acc[t].w};
}

// ---------------- coalesced chunk reduction: Ared = sum_kc Apad ------------
// DIM*NPKP/4 = 147456 float4 -> grid 576 * 256.
__global__ void __launch_bounds__(256) k_reduceA(const float* __restrict__ Apad,
                                                 float* __restrict__ Ared) {
    int idx = blockIdx.x * 256 + threadIdx.x;
    float4 acc = make_float4(0.f, 0.f, 0.f, 0.f);
#pragma unroll
    for (int ch = 0; ch < KCH; ++ch) {
        float4 v = ((const float4*)(Apad + (size_t)ch * DIM * NPKP))[idx];
        acc.x += v.x; acc.y += v.y; acc.z += v.z; acc.w += v.w;
    }
    ((float4*)Ared)[idx] = acc;
}

// ------- invert 16x16 SPD from packed Ared ---------------------------------
// block 128 thr (8 matrices), grid 512.
__global__ void __launch_bounds__(128) k_invert(const float* __restrict__ Ared,
                                                float* __restrict__ Ainv) {
    int gt = blockIdx.x * 128 + threadIdx.x;
    int c = gt >> 4;
    int j = gt & 15;

    float a[16], b[16];
#pragma unroll
    for (int s = 0; s < 16; ++s) {
        int r0 = j < s ? j : s;
        int s0 = j < s ? s : j;
        a[s] = Ared[(size_t)c * NPKP + pidx(r0, s0)];
        b[s] = 0.f;
    }
    a[j] += RIDGE;
    b[j] = 1.f;

#pragma unroll
    for (int k = 0; k < RDIM; ++k) {
        float pivA[16], pivB[16];
#pragma unroll
        for (int s = 0; s < 16; ++s) {
            pivA[s] = __shfl(a[s], k, 16);
            pivB[s] = __shfl(b[s], k, 16);
        }
        float pinv = 1.f / pivA[k];
        float f = a[k];
        if (j == k) {
#pragma unroll
            for (int s = 0; s < 16; ++s) { a[s] = pivA[s] * pinv; b[s] = pivB[s] * pinv; }
        } else {
#pragma unroll
            for (int s = 0; s < 16; ++s) {
                a[s] -= f * pinv * pivA[s];
                b[s] -= f * pinv * pivB[s];
            }
        }
    }
#pragma unroll
    for (int s = 0; s < 16; ++s) Ainv[(size_t)c * 256 + j * 16 + s] = b[s];
}

// ---------------- sigma: sum NSLA spart slices once per column -------------
__global__ void __launch_bounds__(256) k_sig(const float* __restrict__ spart,
                                             const float* __restrict__ cnt,
                                             const float* __restrict__ cvec,
                                             const float* __restrict__ lvec,
                                             int layer, float* __restrict__ sig) {
    __shared__ float red[256];
    int c = blockIdx.x * 64 + (threadIdx.x & 63);
    int part = threadIdx.x >> 6;  // 0..3
    float s = 0.f;
    for (int sl = part * 64; sl < part * 64 + 64; ++sl)
        s += spart[(size_t)sl * DIM + c];
    red[threadIdx.x] = s;
    __syncthreads();
    if (part == 0) {
        s = red[threadIdx.x] + red[threadIdx.x + 64] +
            red[threadIdx.x + 128] + red[threadIdx.x + 192];
        float cl = cvec[layer], ll = lvec[layer];
        float al = alpha_of(cl);
        sig[c] = ll * sqrtf(s) * rsqrtf(2.f * cnt[c] * al);
    }
}

// ---------------- pass 1: psi^2 slice partials, 8 cols/thread --------------
// grid (2, NSLA), block 256.
__global__ void __launch_bounds__(256) k_it_a(const float* __restrict__ Xp,
                                              const float* __restrict__ D,
                                              const float* __restrict__ B,
                                              const float* __restrict__ sig,
                                              const float* __restrict__ sigma,
                                              const float* __restrict__ cvec,
                                              int layer, int use_s0,
                                              float* __restrict__ spart_out) {
    __shared__ float ds[SROWSA * RDIM];  // 1 KB
    const int c = blockIdx.x * 2048 + threadIdx.x * 8;
    const int m0 = blockIdx.y * SROWSA;
    if (threadIdx.x < SROWSA * RDIM / 4)
        ((float4*)ds)[threadIdx.x] = ((const float4*)(D + (size_t)m0 * RDIM))[threadIdx.x];

    float cl = cvec[layer];
    float invsg[8];
    if (use_s0) {
        float is0 = 1.f / sigma[0];
#pragma unroll
        for (int i = 0; i < 8; ++i) invsg[i] = is0;
    } else {
#pragma unroll
        for (int i = 0; i < 8; ++i) invsg[i] = 1.f / sig[c + i];
    }
    float beta[8][16];
#pragma unroll
    for (int i = 0; i < 8; ++i)
#pragma unroll
        for (int q = 0; q < 4; ++q) {
            float4 t4 = ((const float4*)(B + (size_t)(c + i) * RDIM))[q];
            beta[i][q * 4 + 0] = t4.x; beta[i][q * 4 + 1] = t4.y;
            beta[i][q * 4 + 2] = t4.z; beta[i][q * 4 + 3] = t4.w;
        }
    __syncthreads();

    float acc[8];
#pragma unroll
    for (int i = 0; i < 8; ++i) acc[i] = 0.f;

    for (int m = 0; m < SROWSA; ++m) {
        float u[16];
#pragma unroll
        for (int q = 0; q < 4; ++q) {
            float4 u4 = ((const float4*)(ds + m * RDIM))[q];
            u[q * 4 + 0] = u4.x; u[q * 4 + 1] = u4.y;
            u[q * 4 + 2] = u4.z; u[q * 4 + 3] = u4.w;
        }
        const float* xrow = Xp + (size_t)(m0 + m) * DIM + c;
        float4 xa = *(const float4*)xrow;
        float4 xb = *(const float4*)(xrow + 4);
        float xv[8] = {xa.x, xa.y, xa.z, xa.w, xb.x, xb.y, xb.z, xb.w};
#pragma unroll
        for (int i = 0; i < 8; ++i) {
            float dot = 0.f;
#pragma unroll
            for (int s = 0; s < 16; ++s) dot += u[s] * beta[i][s];
            float res = (xv[i] != 0.f) ? (xv[i] - dot) : 0.f;
            float psi = fminf(fmaxf(res * invsg[i], -cl), cl);
            acc[i] += psi * psi;
        }
    }
    float* outp = spart_out + (size_t)blockIdx.y * DIM + c;
    *(float4*)outp       = make_float4(acc[0], acc[1], acc[2], acc[3]);
    *(float4*)(outp + 4) = make_float4(acc[4], acc[5], acc[6], acc[7]);
}

// ---------------- pass 2: t slice partials, 4 cols/thread ------------------
// grid (4, NSL), block 256.
__global__ void __launch_bounds__(256) k_it_c(const float* __restrict__ Xp,
                                              const float* __restrict__ D,
                                              const float* __restrict__ B,
                                              const float* __restrict__ sig,
                                              const float* __restrict__ cvec,
                                              int layer,
                                              float* __restrict__ tpart) {
    __shared__ float ds[SROWS * RDIM];
    const int c = blockIdx.x * 1024 + threadIdx.x * 4;
    const int m0 = blockIdx.y * SROWS;
    if (threadIdx.x < SROWS * RDIM / 4)
        ((float4*)ds)[threadIdx.x] = ((const float4*)(D + (size_t)m0 * RDIM))[threadIdx.x];

    float cl = cvec[layer];
    float sg[4], invsg[4];
#pragma unroll
    for (int i = 0; i < 4; ++i) {
        sg[i] = sig[c + i];
        invsg[i] = 1.f / sg[i];
    }
    float beta[4][16];
#pragma unroll
    for (int i = 0; i < 4; ++i)
#pragma unroll
        for (int q = 0; q < 4; ++q) {
            float4 t4 = ((const float4*)(B + (size_t)(c + i) * RDIM))[q];
            beta[i][q * 4 + 0] = t4.x; beta[i][q * 4 + 1] = t4.y;
            beta[i][q * 4 + 2] = t4.z; beta[i][q * 4 + 3] = t4.w;
        }
    __syncthreads();

    float tac[4][16];
#pragma unroll
    for (int i = 0; i < 4; ++i)
#pragma unroll
        for (int s = 0; s < 16; ++s) tac[i][s] = 0.f;

#pragma unroll 2
    for (int m = 0; m < SROWS; ++m) {
        float u[16];
#pragma unroll
        for (int q = 0; q < 4; ++q) {
            float4 u4 = ((const float4*)(ds + m * RDIM))[q];
            u[q * 4 + 0] = u4.x; u[q * 4 + 1] = u4.y;
            u[q * 4 + 2] = u4.z; u[q * 4 + 3] = u4.w;
        }
        float4 x4 = *(const float4*)(Xp + (size_t)(m0 + m) * DIM + c);
        float xv[4] = {x4.x, x4.y, x4.z, x4.w};
#pragma unroll
        for (int i = 0; i < 4; ++i) {
            float dot = 0.f;
#pragma unroll
            for (int s = 0; s < 16; ++s) dot += u[s] * beta[i][s];
            float res = (xv[i] != 0.f) ? (xv[i] - dot) : 0.f;
            float psi2 = fminf(fmaxf(res * invsg[i], -cl), cl);
            float coeff = psi2 * sg[i];
#pragma unroll
            for (int s = 0; s < 16; ++s) tac[i][s] += u[s] * coeff;
        }
    }
    float* tsl = tpart + (size_t)blockIdx.y * DIM * RDIM;
#pragma unroll
    for (int i = 0; i < 4; ++i)
#pragma unroll
        for (int q = 0; q < 4; ++q)
            *(float4*)(tsl + (size_t)(c + i) * RDIM + q * 4) =
                make_float4(tac[i][q * 4 + 0], tac[i][q * 4 + 1],
                            tac[i][q * 4 + 2], tac[i][q * 4 + 3]);
}

// ------- beta update: B += mu * Ainv @ (sum of tpart slices) ---------------
__global__ void __launch_bounds__(256) k_it_d(const float* __restrict__ Ainv,
                                              const float* __restrict__ tpart,
                                              const float* __restrict__ mvec, int layer,
                                              float* __restrict__ B) {
    __shared__ float t_sh[16][16];
    int c0 = blockIdx.x * 16;
    int cl_ = threadIdx.x >> 4;
    int s = threadIdx.x & 15;
    float tv = 0.f;
#pragma unroll 8
    for (int sl = 0; sl < NSL; ++sl)
        tv += tpart[((size_t)sl * DIM + c0 + cl_) * RDIM + s];
    t_sh[cl_][s] = tv;
    __syncthreads();

    int c = c0 + cl_;
    int j = s;
    float ml = mvec[layer];
    float d = 0.f;
#pragma unroll
    for (int q = 0; q < 4; ++q) {
        float4 a4 = *(const float4*)(Ainv + (size_t)c * 256 + j * 16 + q * 4);
        d += a4.x * t_sh[cl_][q * 4 + 0] + a4.y * t_sh[cl_][q * 4 + 1] +
             a4.z * t_sh[cl_][q * 4 + 2] + a4.w * t_sh[cl_][q * 4 + 3];
    }
    B[(size_t)c * RDIM + j] += ml * d;
}

// ---------------- final out = Uc @ Vtb^T -----------------------------------
__global__ void __launch_bounds__(256) k_out(const float* __restrict__ Uc,
                                             const float* __restrict__ Vtb,
                                             float* __restrict__ out) {
    __shared__ float us[64 * RDIM];
    int j = blockIdx.x * 256 + threadIdx.x;
    int i0 = blockIdx.y * 64;
    ((float4*)us)[threadIdx.x] = ((const float4*)(Uc + (size_t)i0 * RDIM))[threadIdx.x];
    float beta[16];
#pragma unroll
    for (int q = 0; q < 4; ++q) {
        float4 t4 = ((const float4*)(Vtb + (size_t)j * RDIM))[q];
        beta[q * 4 + 0] = t4.x; beta[q * 4 + 1] = t4.y;
        beta[q * 4 + 2] = t4.z; beta[q * 4 + 3] = t4.w;
    }
    __syncthreads();
#pragma unroll 4
    for (int r = 0; r < 64; ++r) {
        float dot = 0.f;
#pragma unroll
        for (int q = 0; q < 4; ++q) {
            float4 u4 = ((const float4*)(us + r * RDIM))[q];
            dot += u4.x * beta[q * 4 + 0] + u4.y * beta[q * 4 + 1] +
                   u4.z * beta[q * 4 + 2] + u4.w * beta[q * 4 + 3];
        }
        out[(size_t)(i0 + r) * DIM + j] = dot;
    }
}

extern "C" void kernel_launch(void* const* d_in, const int* in_sizes, int n_in,
                              void* d_out, int out_size, void* d_ws, size_t ws_size,
                              hipStream_t stream) {
    const float* U = (const float*)d_in[0];
    const float* V = (const float*)d_in[1];
    const float* X = (const float*)d_in[2];
    const float* cvec = (const float*)d_in[3];
    const float* lvec = (const float*)d_in[4];
    const float* mvec = (const float*)d_in[5];
    const float* sigma = (const float*)d_in[6];
    float* out = (float*)d_out;

    float* ws = (float*)d_ws;
    // BIG aliased region: Apad (buildA..reduceA) vs tpart+spart (it-phase).
    // Apad = KCH*4096*144 = 4,718,592 f; tpart = 128*4096*16 = 8,388,608 f;
    // spart @ tpart end (256*4096 = 1,048,576 f). big = 9,437,184 f.
    float* big    = ws;
    float* Apad   = big;
    float* tpart  = big;
    float* spart  = big + (size_t)NSL * DIM * RDIM;
    float* endbig = big + (size_t)NSL * DIM * RDIM + (size_t)NSLA * DIM;
    float* Ared   = endbig;                       // 4096*144 = 589,824
    float* Ainv   = Ared + (size_t)DIM * NPKP;    // 4096*256
    float* sigbuf = Ainv + (size_t)DIM * 256;     // 4096
    float* cntc   = sigbuf + DIM;                 // 4096
    float* cntr   = cntc + DIM;                   // 4096
    float* Uc     = cntr + DIM;                   // 4096*16
    float* Vtb    = Uc + (size_t)DIM * RDIM;      // 4096*16
    unsigned short* Pt = (unsigned short*)(Vtb + (size_t)DIM * RDIM); // 144*4096 u16
    float* Xt     = out;  // reuse d_out as transpose scratch until k_out

    // zero only the atomic targets (cntc, cntr — contiguous)
    hipMemsetAsync(cntc, 0, (size_t)2 * DIM * sizeof(float), stream);

    k_transpose<<<dim3(64, 64), 256, 0, stream>>>(X, Xt);
    k_init_uc<<<64, 256, 0, stream>>>(U, Uc);
    k_init_vt<<<16, 256, 0, stream>>>(V, Vtb);
    k_count<<<dim3(16, 16), 256, 0, stream>>>(X, cntc);
    k_count<<<dim3(16, 16), 256, 0, stream>>>(Xt, cntr);

    for (int layer = 0; layer < 3; ++layer) {
        // ---- V step: per-column A from design Uc; B-operand rows from Xt ----
        k_prep<<<dim3(16, NPKP), 256, 0, stream>>>(Uc, Pt);
        k_buildA_mfma<<<dim3(64, KCH), 256, 0, stream>>>(Xt, Pt, Apad);
        k_reduceA<<<576, 256, 0, stream>>>(Apad, Ared);
        k_invert<<<512, 128, 0, stream>>>(Ared, Ainv);
        k_it_a<<<dim3(2, NSLA), 256, 0, stream>>>(X, Uc, Vtb, sigbuf, sigma, cvec,
                                                  layer, 1, spart);
        k_sig<<<64, 256, 0, stream>>>(spart, cntc, cvec, lvec, layer, sigbuf);
        k_it_c<<<dim3(4, NSL), 256, 0, stream>>>(X, Uc, Vtb, sigbuf, cvec, layer, tpart);
        k_it_d<<<256, 256, 0, stream>>>(Ainv, tpart, mvec, layer, Vtb);
        k_it_a<<<dim3(2, NSLA), 256, 0, stream>>>(X, Uc, Vtb, sigbuf, sigma, cvec,
                                                  layer, 0, spart);
        k_sig<<<64, 256, 0, stream>>>(spart, cntc, cvec, lvec, layer, sigbuf);
        k_it_c<<<dim3(4, NSL), 256, 0, stream>>>(X, Uc, Vtb, sigbuf, cvec, layer, tpart);
        k_it_d<<<256, 256, 0, stream>>>(Ainv, tpart, mvec, layer, Vtb);

        // ---- U step: per-row A from design Vtb; B-operand rows from X ----
        k_prep<<<dim3(16, NPKP), 256, 0, stream>>>(Vtb, Pt);
        k_buildA_mfma<<<dim3(64, KCH), 256, 0, stream>>>(X, Pt, Apad);
        k_reduceA<<<576, 256, 0, stream>>>(Apad, Ared);
        k_invert<<<512, 128, 0, stream>>>(Ared, Ainv);
        k_it_a<<<dim3(2, NSLA), 256, 0, stream>>>(Xt, Vtb, Uc, sigbuf, sigma, cvec,
                                                  layer, 1, spart);
        k_sig<<<64, 256, 0, stream>>>(spart, cntr, cvec, lvec, layer, sigbuf);
        k_it_c<<<dim3(4, NSL), 256, 0, stream>>>(Xt, Vtb, Uc, sigbuf, cvec, layer, tpart);
        k_it_d<<<256, 256, 0, stream>>>(Ainv, tpart, mvec, layer, Uc);
        k_it_a<<<dim3(2, NSLA), 256, 0, stream>>>(Xt, Vtb, Uc, sigbuf, sigma, cvec,
                                                  layer, 0, spart);
        k_sig<<<64, 256, 0, stream>>>(spart, cntr, cvec, lvec, layer, sigbuf);
        k_it_c<<<dim3(4, NSL), 256, 0, stream>>>(Xt, Vtb, Uc, sigbuf, cvec, layer, tpart);
        k_it_d<<<256, 256, 0, stream>>>(Ainv, tpart, mvec, layer, Uc);
    }
    k_out<<<dim3(16, 64), 256, 0, stream>>>(Uc, Vtb, out);
}

// Round 7
// 1335.774 us; speedup vs baseline: 1.5850x; 1.1683x over previous
//
#include <hip/hip_runtime.h>
#include <math.h>

#define DIM 4096
#define RDIM 16
#define RIDGE 1e-5f
#define NPKP 144    // padded pair count (9 MFMA tiles of 16)
#define KCH 8       // K-chunks for MFMA buildA
#define KT 128      // k-tile staged in LDS per buildA inner iteration
#define NSL 128     // tpart slices (= grid.y of it_c)
#define SROWS 32    // rows per it_c block
#define NSLA 256    // spart slices (= grid.y of it_a)
#define SROWSA 16   // rows per it_a block

typedef __attribute__((ext_vector_type(8))) short bf16x8;
typedef __attribute__((ext_vector_type(4))) float f32x4;

__device__ __forceinline__ int pidx(int r, int s) { return r * (31 - r) / 2 + s; } // r<=s

__device__ __forceinline__ float alpha_of(float cl) {
    return cl * (1.f - erff(sqrtf(cl))) +
           0.5f * (erff(cl * 0.70710678118f) -
                   0.79788456080f * cl * expf(-0.5f * cl * cl));
}

// ------- transpose X -> Xt, fused per-column and per-row observed counts ---
__global__ void __launch_bounds__(256) k_transpose(const float* __restrict__ X,
                                                   float* __restrict__ Xt,
                                                   float* __restrict__ cntc,
                                                   float* __restrict__ cntr) {
    __shared__ float tile[64][65];
    __shared__ float redc[4][64];
    __shared__ float redr[4][64];
    int bx = blockIdx.x, by = blockIdx.y;
    int lx = threadIdx.x & 63;
    int ly = threadIdx.x >> 6;
    float ccnt = 0.f;
#pragma unroll
    for (int i = 0; i < 16; ++i) {
        int r = ly + i * 4;
        float v = X[(size_t)(by * 64 + r) * DIM + bx * 64 + lx];
        tile[r][lx] = v;
        ccnt += (v != 0.f) ? 1.f : 0.f;
    }
    redc[ly][lx] = ccnt;
    __syncthreads();
#pragma unroll
    for (int i = 0; i < 16; ++i) {
        int r = ly + i * 4;
        Xt[(size_t)(bx * 64 + r) * DIM + by * 64 + lx] = tile[lx][r];
    }
    // row counts: thread (lx,ly) counts X row by*64+lx over 16 cols
    float rcnt = 0.f;
#pragma unroll
    for (int j = 0; j < 16; ++j)
        rcnt += (tile[lx][ly * 16 + j] != 0.f) ? 1.f : 0.f;
    redr[ly][lx] = rcnt;
    __syncthreads();
    if (threadIdx.x < 64) {
        int c = threadIdx.x;
        atomicAdd(&cntc[bx * 64 + c],
                  redc[0][c] + redc[1][c] + redc[2][c] + redc[3][c]);
    } else if (threadIdx.x < 128) {
        int r = threadIdx.x - 64;
        atomicAdd(&cntr[by * 64 + r],
                  redr[0][r] + redr[1][r] + redr[2][r] + redr[3][r]);
    }
}

// ---------------- init copies ----------------------------------------------
__global__ void k_init_uc(const float* __restrict__ U, float* __restrict__ Uc) {
    int i = blockIdx.x * 256 + threadIdx.x;
    ((float4*)Uc)[i] = ((const float4*)U)[i];
}
__global__ void k_init_vt(const float* __restrict__ V, float* __restrict__ Vtb) {
    int n = blockIdx.x * 256 + threadIdx.x;
#pragma unroll
    for (int r = 0; r < RDIM; ++r) Vtb[(size_t)n * RDIM + r] = V[(size_t)r * DIM + n];
}

// ---------------- Pt[rs][m] = bf16(D[m][r] * D[m][s]), pidx order ----------
// grid (16 m-chunks, NPKP), block 256.
__global__ void __launch_bounds__(256) k_prep(const float* __restrict__ D,
                                              unsigned short* __restrict__ Pt) {
    int rs = blockIdx.y;
    int rr = 16, ss = 0;
#pragma unroll
    for (int r = 0; r < 16; ++r) {
        int base = r * (31 - r) / 2;
        if (rs >= base + r && rs <= base + 15) { rr = r; ss = rs - base; }
    }
    int m = blockIdx.x * 256 + threadIdx.x;
    float p = 0.f;
    if (rr < 16) p = D[(size_t)m * RDIM + rr] * D[(size_t)m * RDIM + ss];
    unsigned bits = __float_as_uint(p);
    unsigned short h = (unsigned short)((bits + 0x7FFFu + ((bits >> 16) & 1u)) >> 16);
    Pt[(size_t)rs * DIM + m] = h;
}

// ---------------- MFMA buildA, LDS-staged operands -------------------------
// grid (64, KCH), block 256 = 4 waves. Block covers 64 c-rows of XpT;
// per KT=128 k-tile, stage mask (64x128 bf16) + Pt (144x128 bf16) in LDS.
__global__ void __launch_bounds__(256) k_buildA_mfma(const float* __restrict__ XpT,
                                                     const unsigned short* __restrict__ Pt,
                                                     float* __restrict__ Apad) {
    __shared__ unsigned short wtile[64][136];   // +8 bf16 pad (16 B) per row
    __shared__ unsigned short ptile[144][136];
    const int wave = threadIdx.x >> 6;
    const int lane = threadIdx.x & 63;
    const int n = lane & 15;
    const int quad = lane >> 4;
    const int c0 = blockIdx.x * 64;
    const int kbase0 = blockIdx.y * (DIM / KCH);
    const int r0 = threadIdx.x >> 5;        // 0..7
    const int col4 = (threadIdx.x & 31) * 4;

    f32x4 acc[9];
#pragma unroll
    for (int t = 0; t < 9; ++t) acc[t] = (f32x4){0.f, 0.f, 0.f, 0.f};

    for (int kt = 0; kt < (DIM / KCH) / KT; ++kt) {   // 4 iterations
        const int kb = kbase0 + kt * KT;
        __syncthreads();
        // stage W mask: coalesced float4 reads, convert to bf16 0/1
#pragma unroll
        for (int j = 0; j < 8; ++j) {
            int r = r0 + 8 * j;
            float4 v = *(const float4*)(XpT + (size_t)(c0 + r) * DIM + kb + col4);
            ushort4 mk;
            mk.x = (v.x != 0.f) ? 0x3F80 : 0;
            mk.y = (v.y != 0.f) ? 0x3F80 : 0;
            mk.z = (v.z != 0.f) ? 0x3F80 : 0;
            mk.w = (v.w != 0.f) ? 0x3F80 : 0;
            *(ushort4*)&wtile[r][col4] = mk;
        }
        // stage Pt: 144 rows x 128 bf16 = 2304 16B-chunks = 256 thr x 9
#pragma unroll
        for (int j = 0; j < 9; ++j) {
            int idx = j * 256 + threadIdx.x;
            int pr = idx >> 4;
            int pc = (idx & 15) * 8;
            *(uint4*)&ptile[pr][pc] = *(const uint4*)(Pt + (size_t)pr * DIM + kb + pc);
        }
        __syncthreads();
        // MFMA over the staged tile
#pragma unroll
        for (int inner = 0; inner < 4; ++inner) {
            bf16x8 bfrag = *(const bf16x8*)&wtile[wave * 16 + n][inner * 32 + quad * 8];
#pragma unroll
            for (int t = 0; t < 9; ++t) {
                bf16x8 afrag = *(const bf16x8*)&ptile[t * 16 + n][inner * 32 + quad * 8];
                acc[t] = __builtin_amdgcn_mfma_f32_16x16x32_bf16(afrag, bfrag, acc[t], 0, 0, 0);
            }
        }
    }
    // C/D layout: col = lane&15 (c), row = quad*4 + reg (rs within tile)
    const int c = c0 + wave * 16 + n;
    float* dst0 = Apad + ((size_t)blockIdx.y * DIM + c) * NPKP + quad * 4;
#pragma unroll
    for (int t = 0; t < 9; ++t)
        *(float4*)(dst0 + t * 16) = (float4){acc[t].x, acc[t].y, acc[t].z, acc[t].w};
}

// ------- invert 16x16 SPD; chunk reduction fused ---------------------------
// block 128 thr (8 matrices), grid 512.
__global__ void __launch_bounds__(128) k_invert(const float* __restrict__ Apad,
                                                float* __restrict__ Ainv) {
    int gt = blockIdx.x * 128 + threadIdx.x;
    int c = gt >> 4;
    int j = gt & 15;

    float a[16], b[16];
#pragma unroll
    for (int s = 0; s < 16; ++s) {
        int r0 = j < s ? j : s;
        int s0 = j < s ? s : j;
        int off = pidx(r0, s0);
        float acc = 0.f;
#pragma unroll
        for (int ch = 0; ch < KCH; ++ch)
            acc += Apad[((size_t)ch * DIM + c) * NPKP + off];
        a[s] = acc;
        b[s] = 0.f;
    }
    a[j] += RIDGE;
    b[j] = 1.f;

#pragma unroll
    for (int k = 0; k < RDIM; ++k) {
        float pivA[16], pivB[16];
#pragma unroll
        for (int s = 0; s < 16; ++s) {
            pivA[s] = __shfl(a[s], k, 16);
            pivB[s] = __shfl(b[s], k, 16);
        }
        float pinv = 1.f / pivA[k];
        float f = a[k];
        if (j == k) {
#pragma unroll
            for (int s = 0; s < 16; ++s) { a[s] = pivA[s] * pinv; b[s] = pivB[s] * pinv; }
        } else {
#pragma unroll
            for (int s = 0; s < 16; ++s) {
                a[s] -= f * pinv * pivA[s];
                b[s] -= f * pinv * pivB[s];
            }
        }
    }
#pragma unroll
    for (int s = 0; s < 16; ++s) Ainv[(size_t)c * 256 + j * 16 + s] = b[s];
}

// ---------------- sigma: sum NSLA spart slices once per column -------------
__global__ void __launch_bounds__(256) k_sig(const float* __restrict__ spart,
                                             const float* __restrict__ cnt,
                                             const float* __restrict__ cvec,
                                             const float* __restrict__ lvec,
                                             int layer, float* __restrict__ sig) {
    __shared__ float red[256];
    int c = blockIdx.x * 64 + (threadIdx.x & 63);
    int part = threadIdx.x >> 6;  // 0..3
    float s = 0.f;
    for (int sl = part * 64; sl < part * 64 + 64; ++sl)
        s += spart[(size_t)sl * DIM + c];
    red[threadIdx.x] = s;
    __syncthreads();
    if (part == 0) {
        s = red[threadIdx.x] + red[threadIdx.x + 64] +
            red[threadIdx.x + 128] + red[threadIdx.x + 192];
        float cl = cvec[layer], ll = lvec[layer];
        float al = alpha_of(cl);
        sig[c] = ll * sqrtf(s) * rsqrtf(2.f * cnt[c] * al);
    }
}

// ---------------- pass 1: psi^2 slice partials, 4 cols/thread --------------
// grid (4, NSLA), block 256.
__global__ void __launch_bounds__(256) k_it_a(const float* __restrict__ Xp,
                                              const float* __restrict__ D,
                                              const float* __restrict__ B,
                                              const float* __restrict__ sig,
                                              const float* __restrict__ sigma,
                                              const float* __restrict__ cvec,
                                              int layer, int use_s0,
                                              float* __restrict__ spart_out) {
    __shared__ float ds[SROWSA * RDIM];  // 1 KB
    const int c = blockIdx.x * 1024 + threadIdx.x * 4;
    const int m0 = blockIdx.y * SROWSA;
    if (threadIdx.x < SROWSA * RDIM / 4)
        ((float4*)ds)[threadIdx.x] = ((const float4*)(D + (size_t)m0 * RDIM))[threadIdx.x];

    float cl = cvec[layer];
    float invsg[4];
    if (use_s0) {
        float is0 = 1.f / sigma[0];
#pragma unroll
        for (int i = 0; i < 4; ++i) invsg[i] = is0;
    } else {
#pragma unroll
        for (int i = 0; i < 4; ++i) invsg[i] = 1.f / sig[c + i];
    }
    float beta[4][16];
#pragma unroll
    for (int i = 0; i < 4; ++i)
#pragma unroll
        for (int q = 0; q < 4; ++q) {
            float4 t4 = ((const float4*)(B + (size_t)(c + i) * RDIM))[q];
            beta[i][q * 4 + 0] = t4.x; beta[i][q * 4 + 1] = t4.y;
            beta[i][q * 4 + 2] = t4.z; beta[i][q * 4 + 3] = t4.w;
        }
    __syncthreads();

    float acc[4] = {0.f, 0.f, 0.f, 0.f};
    for (int m = 0; m < SROWSA; ++m) {
        float u[16];
#pragma unroll
        for (int q = 0; q < 4; ++q) {
            float4 u4 = ((const float4*)(ds + m * RDIM))[q];
            u[q * 4 + 0] = u4.x; u[q * 4 + 1] = u4.y;
            u[q * 4 + 2] = u4.z; u[q * 4 + 3] = u4.w;
        }
        float4 x4 = *(const float4*)(Xp + (size_t)(m0 + m) * DIM + c);
        float xv[4] = {x4.x, x4.y, x4.z, x4.w};
#pragma unroll
        for (int i = 0; i < 4; ++i) {
            float dot = 0.f;
#pragma unroll
            for (int s = 0; s < 16; ++s) dot += u[s] * beta[i][s];
            float res = (xv[i] != 0.f) ? (xv[i] - dot) : 0.f;
            float psi = fminf(fmaxf(res * invsg[i], -cl), cl);
            acc[i] += psi * psi;
        }
    }
    *(float4*)(spart_out + (size_t)blockIdx.y * DIM + c) =
        make_float4(acc[0], acc[1], acc[2], acc[3]);
}

// ---------------- pass 2: t slice partials, 4 cols/thread ------------------
// grid (4, NSL), block 256.
__global__ void __launch_bounds__(256) k_it_c(const float* __restrict__ Xp,
                                              const float* __restrict__ D,
                                              const float* __restrict__ B,
                                              const float* __restrict__ sig,
                                              const float* __restrict__ cvec,
                                              int layer,
                                              float* __restrict__ tpart) {
    __shared__ float ds[SROWS * RDIM];
    const int c = blockIdx.x * 1024 + threadIdx.x * 4;
    const int m0 = blockIdx.y * SROWS;
    if (threadIdx.x < SROWS * RDIM / 4)
        ((float4*)ds)[threadIdx.x] = ((const float4*)(D + (size_t)m0 * RDIM))[threadIdx.x];

    float cl = cvec[layer];
    float sg[4], invsg[4];
#pragma unroll
    for (int i = 0; i < 4; ++i) {
        sg[i] = sig[c + i];
        invsg[i] = 1.f / sg[i];
    }
    float beta[4][16];
#pragma unroll
    for (int i = 0; i < 4; ++i)
#pragma unroll
        for (int q = 0; q < 4; ++q) {
            float4 t4 = ((const float4*)(B + (size_t)(c + i) * RDIM))[q];
            beta[i][q * 4 + 0] = t4.x; beta[i][q * 4 + 1] = t4.y;
            beta[i][q * 4 + 2] = t4.z; beta[i][q * 4 + 3] = t4.w;
        }
    __syncthreads();

    float tac[4][16];
#pragma unroll
    for (int i = 0; i < 4; ++i)
#pragma unroll
        for (int s = 0; s < 16; ++s) tac[i][s] = 0.f;

#pragma unroll 2
    for (int m = 0; m < SROWS; ++m) {
        float u[16];
#pragma unroll
        for (int q = 0; q < 4; ++q) {
            float4 u4 = ((const float4*)(ds + m * RDIM))[q];
            u[q * 4 + 0] = u4.x; u[q * 4 + 1] = u4.y;
            u[q * 4 + 2] = u4.z; u[q * 4 + 3] = u4.w;
        }
        float4 x4 = *(const float4*)(Xp + (size_t)(m0 + m) * DIM + c);
        float xv[4] = {x4.x, x4.y, x4.z, x4.w};
#pragma unroll
        for (int i = 0; i < 4; ++i) {
            float dot = 0.f;
#pragma unroll
            for (int s = 0; s < 16; ++s) dot += u[s] * beta[i][s];
            float res = (xv[i] != 0.f) ? (xv[i] - dot) : 0.f;
            float psi2 = fminf(fmaxf(res * invsg[i], -cl), cl);
            float coeff = psi2 * sg[i];
#pragma unroll
            for (int s = 0; s < 16; ++s) tac[i][s] += u[s] * coeff;
        }
    }
    float* tsl = tpart + (size_t)blockIdx.y * DIM * RDIM;
#pragma unroll
    for (int i = 0; i < 4; ++i)
#pragma unroll
        for (int q = 0; q < 4; ++q)
            *(float4*)(tsl + (size_t)(c + i) * RDIM + q * 4) =
                make_float4(tac[i][q * 4 + 0], tac[i][q * 4 + 1],
                            tac[i][q * 4 + 2], tac[i][q * 4 + 3]);
}

// ------- beta update: B += mu * Ainv @ (sum of tpart slices) ---------------
__global__ void __launch_bounds__(256) k_it_d(const float* __restrict__ Ainv,
                                              const float* __restrict__ tpart,
                                              const float* __restrict__ mvec, int layer,
                                              float* __restrict__ B) {
    __shared__ float t_sh[16][16];
    int c0 = blockIdx.x * 16;
    int cl_ = threadIdx.x >> 4;
    int s = threadIdx.x & 15;
    float tv = 0.f;
#pragma unroll 8
    for (int sl = 0; sl < NSL; ++sl)
        tv += tpart[((size_t)sl * DIM + c0 + cl_) * RDIM + s];
    t_sh[cl_][s] = tv;
    __syncthreads();

    int c = c0 + cl_;
    int j = s;
    float ml = mvec[layer];
    float d = 0.f;
#pragma unroll
    for (int q = 0; q < 4; ++q) {
        float4 a4 = *(const float4*)(Ainv + (size_t)c * 256 + j * 16 + q * 4);
        d += a4.x * t_sh[cl_][q * 4 + 0] + a4.y * t_sh[cl_][q * 4 + 1] +
             a4.z * t_sh[cl_][q * 4 + 2] + a4.w * t_sh[cl_][q * 4 + 3];
    }
    B[(size_t)c * RDIM + j] += ml * d;
}

// ---------------- final out = Uc @ Vtb^T -----------------------------------
__global__ void __launch_bounds__(256) k_out(const float* __restrict__ Uc,
                                             const float* __restrict__ Vtb,
                                             float* __restrict__ out) {
    __shared__ float us[64 * RDIM];
    int j = blockIdx.x * 256 + threadIdx.x;
    int i0 = blockIdx.y * 64;
    ((float4*)us)[threadIdx.x] = ((const float4*)(Uc + (size_t)i0 * RDIM))[threadIdx.x];
    float beta[16];
#pragma unroll
    for (int q = 0; q < 4; ++q) {
        float4 t4 = ((const float4*)(Vtb + (size_t)j * RDIM))[q];
        beta[q * 4 + 0] = t4.x; beta[q * 4 + 1] = t4.y;
        beta[q * 4 + 2] = t4.z; beta[q * 4 + 3] = t4.w;
    }
    __syncthreads();
#pragma unroll 4
    for (int r = 0; r < 64; ++r) {
        float dot = 0.f;
#pragma unroll
        for (int q = 0; q < 4; ++q) {
            float4 u4 = ((const float4*)(us + r * RDIM))[q];
            dot += u4.x * beta[q * 4 + 0] + u4.y * beta[q * 4 + 1] +
                   u4.z * beta[q * 4 + 2] + u4.w * beta[q * 4 + 3];
        }
        out[(size_t)(i0 + r) * DIM + j] = dot;
    }
}

extern "C" void kernel_launch(void* const* d_in, const int* in_sizes, int n_in,
                              void* d_out, int out_size, void* d_ws, size_t ws_size,
                              hipStream_t stream) {
    const float* U = (const float*)d_in[0];
    const float* V = (const float*)d_in[1];
    const float* X = (const float*)d_in[2];
    const float* cvec = (const float*)d_in[3];
    const float* lvec = (const float*)d_in[4];
    const float* mvec = (const float*)d_in[5];
    const float* sigma = (const float*)d_in[6];
    float* out = (float*)d_out;

    float* ws = (float*)d_ws;
    // BIG aliased region: Apad (buildA..invert) vs tpart+spart (it-phase).
    // Apad = KCH*4096*144 = 4,718,592 f; tpart = 128*4096*16 = 8,388,608 f;
    // spart @ tpart end (256*4096 = 1,048,576 f). big = 9,437,184 f.
    float* big    = ws;
    float* Apad   = big;
    float* tpart  = big;
    float* spart  = big + (size_t)NSL * DIM * RDIM;
    float* endbig = big + (size_t)NSL * DIM * RDIM + (size_t)NSLA * DIM;
    float* Ainv   = endbig;                       // 4096*256
    float* sigbuf = Ainv + (size_t)DIM * 256;     // 4096
    float* cntc   = sigbuf + DIM;                 // 4096
    float* cntr   = cntc + DIM;                   // 4096
    float* Uc     = cntr + DIM;                   // 4096*16
    float* Vtb    = Uc + (size_t)DIM * RDIM;      // 4096*16
    unsigned short* Pt = (unsigned short*)(Vtb + (size_t)DIM * RDIM); // 144*4096 u16
    float* Xt     = out;  // reuse d_out as transpose scratch until k_out

    // zero only the atomic targets (cntc, cntr — contiguous)
    hipMemsetAsync(cntc, 0, (size_t)2 * DIM * sizeof(float), stream);

    k_transpose<<<dim3(64, 64), 256, 0, stream>>>(X, Xt, cntc, cntr);
    k_init_uc<<<64, 256, 0, stream>>>(U, Uc);
    k_init_vt<<<16, 256, 0, stream>>>(V, Vtb);

    for (int layer = 0; layer < 3; ++layer) {
        // ---- V step: per-column A from design Uc; B-operand rows from Xt ----
        k_prep<<<dim3(16, NPKP), 256, 0, stream>>>(Uc, Pt);
        k_buildA_mfma<<<dim3(64, KCH), 256, 0, stream>>>(Xt, Pt, Apad);
        k_invert<<<512, 128, 0, stream>>>(Apad, Ainv);
        k_it_a<<<dim3(4, NSLA), 256, 0, stream>>>(X, Uc, Vtb, sigbuf, sigma, cvec,
                                                  layer, 1, spart);
        k_sig<<<64, 256, 0, stream>>>(spart, cntc, cvec, lvec, layer, sigbuf);
        k_it_c<<<dim3(4, NSL), 256, 0, stream>>>(X, Uc, Vtb, sigbuf, cvec, layer, tpart);
        k_it_d<<<256, 256, 0, stream>>>(Ainv, tpart, mvec, layer, Vtb);
        k_it_a<<<dim3(4, NSLA), 256, 0, stream>>>(X, Uc, Vtb, sigbuf, sigma, cvec,
                                                  layer, 0, spart);
        k_sig<<<64, 256, 0, stream>>>(spart, cntc, cvec, lvec, layer, sigbuf);
        k_it_c<<<dim3(4, NSL), 256, 0, stream>>>(X, Uc, Vtb, sigbuf, cvec, layer, tpart);
        k_it_d<<<256, 256, 0, stream>>>(Ainv, tpart, mvec, layer, Vtb);

        // ---- U step: per-row A from design Vtb; B-operand rows from X ----
        k_prep<<<dim3(16, NPKP), 256, 0, stream>>>(Vtb, Pt);
        k_buildA_mfma<<<dim3(64, KCH), 256, 0, stream>>>(X, Pt, Apad);
        k_invert<<<512, 128, 0, stream>>>(Apad, Ainv);
        k_it_a<<<dim3(4, NSLA), 256, 0, stream>>>(Xt, Vtb, Uc, sigbuf, sigma, cvec,
                                                  layer, 1, spart);
        k_sig<<<64, 256, 0, stream>>>(spart, cntr, cvec, lvec, layer, sigbuf);
        k_it_c<<<dim3(4, NSL), 256, 0, stream>>>(Xt, Vtb, Uc, sigbuf, cvec, layer, tpart);
        k_it_d<<<256, 256, 0, stream>>>(Ainv, tpart, mvec, layer, Uc);
        k_it_a<<<dim3(4, NSLA), 256, 0, stream>>>(Xt, Vtb, Uc, sigbuf, sigma, cvec,
                                                  layer, 0, spart);
        k_sig<<<64, 256, 0, stream>>>(spart, cntr, cvec, lvec, layer, sigbuf);
        k_it_c<<<dim3(4, NSL), 256, 0, stream>>>(Xt, Vtb, Uc, sigbuf, cvec, layer, tpart);
        k_it_d<<<256, 256, 0, stream>>>(Ainv, tpart, mvec, layer, Uc);
    }
    k_out<<<dim3(16, 64), 256, 0, stream>>>(Uc, Vtb, out);
}